// Round 8
// baseline (243.163 us; speedup 1.0000x reference)
//
#include <hip/hip_runtime.h>

// LightGCN propagation: 3x SpMM over fixed COO graph + batched dot epilogue.
// R21: build-phase restructure.
// (1) p4f single-atomic-pass: hist uses RETURNING atomicAdd -> per-edge
//     rank rr[u] (static regs); after scan, iperm[rs_[dl]+rr[u]]=i is
//     atomic-free (same trick R17 proved in part). Removes one full
//     9.4K-atomic barrier-bounded phase per block.
// (2) fp32->bf16 conv blocks moved from part's grid to p4f's grid: conv
//     (BW-bound, 0 LDS) co-resides with p4f sort blocks (latency-bound,
//     108KB LDS) on the same CUs -> ~77MB stream hidden under the sort;
//     part (512 sort blocks) finishes sooner.
// R20: part CHUNKS=512 (2 blocks/CU), p4f coalesced write-back via LDS
// inverse permutation. R18: part = LDS counting sort, coalesced run
// write-out, padded gcur. spmm (R16): 8 nodes/wave octets, cooperative
// 64B epair fetch, 8-deep row-gather MLP; at the ~3.5TB/s random-128B-
// gather fabric ceiling (FETCH = 8 XCD x ~81% table, compulsory).
// Layer 3 batch-only (R10). bf16 rows (R5).

#define N_USERS 50000
#define N_ITEMS 100000
#define N_NODES 150000
#define N_EDGES 2400000
#define DIM 64
#define BATCH 4096

#define CHUNKS 512
#define CHUNK_EDGES 4688   // 512*4688 = 2400256 >= N_EDGES (tail guarded)
#define PPT 5              // ceil(4688/1024) edges per thread per pass
#define KB 256             // super-buckets
#define NPB 586            // nodes per bucket; 256*586 = 150016 >= N_NODES
#define ECAP 10240         // bucket capacity: mean 9375, sigma 97 -> +8.9 sigma
#define MAXIT 10           // ECAP/1024 strided iterations in p4f
#define GSTR 16            // gcur stride: 1 counter per 64B line
#define CONVB 2344         // ceil(2400000 float4 / 1024)

typedef unsigned int uint;
typedef float v2f __attribute__((ext_vector_type(2)));

__device__ __forceinline__ uint pack_bf16(float a, float b) {
    uint ua = __float_as_uint(a), ub = __float_as_uint(b);
    ua = (ua + 0x7FFFu + ((ua >> 16) & 1u)) >> 16;   // RTNE
    ub = (ub + 0x7FFFu + ((ub >> 16) & 1u)) >> 16;
    return ua | (ub << 16);
}

__device__ __forceinline__ v2f unpack_bf16x2(uint w) {
    v2f r;
    r.x = __uint_as_float(w << 16);
    r.y = __uint_as_float(w & 0xFFFF0000u);
    return r;
}

// PART: LDS counting sort of each chunk's edges by super-bucket, then
// coalesced segment write-out into reserved fat runs. 2 blocks/CU.
__global__ __launch_bounds__(1024) void part_kernel(
        const int* __restrict__ src, const int* __restrict__ dstA,
        const float* __restrict__ vals, int* __restrict__ gcur,
        int2* __restrict__ coarse) {
    int t = threadIdx.x;
    __shared__ int2 stage[CHUNK_EDGES];              // 37504 B sorted payload
    __shared__ unsigned char stage_b[CHUNK_EDGES];   // 4688 B bucket ids
    __shared__ int h[KB];
    __shared__ int hoff[KB];
    __shared__ int delta[KB];
    __shared__ int wsum4[4];
    int c = blockIdx.x;
    if (t < KB) h[t] = 0;
    __syncthreads();
    int base = c * CHUNK_EDGES;
    int ecnt = min(CHUNK_EDGES, N_EDGES - base);     // tail chunk short
    int d_c[PPT];
    int r_c[PPT];
#pragma unroll
    for (int u = 0; u < PPT; ++u) {
        int i = t + u * 1024;
        d_c[u] = 0;
        r_c[u] = 0;
        if (i < ecnt) {
            int d = dstA[base + i];
            d_c[u] = d;
            // returning atomic: rank within (chunk,bucket); independent ->
            // pipelined across the unrolled iterations.
            r_c[u] = atomicAdd(&h[(int)((unsigned)d / NPB)], 1);
        }
    }
    __syncthreads();
    int lane = t & 63, wid = t >> 6;
    if (t < KB) {                     // 4-wave scan of 256 bucket counts
        int v = h[t];
        int incl = v;
#pragma unroll
        for (int o = 1; o < 64; o <<= 1) {
            int add = __shfl_up(incl, o, 64);
            if (lane >= o) incl += add;
        }
        hoff[t] = incl - v;
        if (lane == 63) wsum4[wid] = incl;
    }
    __syncthreads();
    if (t < 64) {
        int vv = (lane < 4) ? wsum4[lane] : 0;
        int inc2 = vv;
#pragma unroll
        for (int o = 1; o < 4; o <<= 1) {
            int add = __shfl_up(inc2, o, 64);
            if (lane >= o) inc2 += add;
        }
        if (lane < 4) wsum4[lane] = inc2 - vv;
    }
    __syncthreads();
    if (t < KB) {
        int off = hoff[t] + wsum4[t >> 6];           // chunk-local bucket start
        hoff[t] = off;
        int cb = atomicAdd(&gcur[t * GSTR], h[t]);   // reserve fat run (padded)
        delta[t] = t * ECAP + cb - off;              // sorted-pos -> coarse idx
    }
    __syncthreads();
    // pass 1.5: stage edges into sorted LDS slots
#pragma unroll
    for (int u = 0; u < PPT; ++u) {
        int i = t + u * 1024;
        if (i < ecnt) {
            int e = base + i;
            int d = d_c[u];
            int b = (int)((unsigned)d / NPB);
            int dl = d - b * NPB;
            int pos = hoff[b] + r_c[u];
            stage[pos] = make_int2(src[e] | (dl << 18), __float_as_int(vals[e]));
            stage_b[pos] = (unsigned char)b;
        }
    }
    __syncthreads();
    // pass 2: coalesced write-out (consecutive j -> consecutive coarse idx
    // within each per-bucket run of ~18 edges)
#pragma unroll
    for (int u = 0; u < PPT; ++u) {
        int j = t + u * 1024;
        if (j < ecnt) {
            int b = stage_b[j];
            int idx = j + delta[b];
            if (idx < (b + 1) * ECAP)                // overflow guard
                coarse[idx] = stage[j];
        }
    }
}

// P4F: blocks [0,KB): per-super-bucket fine sort IN PLACE -- edges -> LDS,
// RETURNING-atomic hist (rank in regs), wave-shuffle scan, rowinfo emit,
// atomic-free inverse permutation, coalesced write-back.
// Blocks [KB,..): fp32 -> bf16 concat t0 (co-resident: 0 LDS, BW-bound,
// overlaps the latency-bound sort blocks).
__global__ __launch_bounds__(1024) void p4f_fine(
        int2* __restrict__ coarse, const int* __restrict__ gcur,
        uint* __restrict__ rowinfo,
        const float* __restrict__ emb_user, const float* __restrict__ emb_item,
        uint2* __restrict__ t0) {
    int t = threadIdx.x;
    if (blockIdx.x >= KB) {
        int i = (blockIdx.x - KB) * 1024 + t;  // float4 index, 2.4M total
        if (i < N_NODES * DIM / 4) {
            const int userN4 = N_USERS * DIM / 4; // 800000
            float4 v;
            if (i < userN4) v = ((const float4*)emb_user)[i];
            else            v = ((const float4*)emb_item)[i - userN4];
            t0[i] = make_uint2(pack_bf16(v.x, v.y), pack_bf16(v.z, v.w));
        }
        return;
    }
    __shared__ int2 eds[ECAP];              // 81920 B
    __shared__ unsigned short iperm[ECAP];  // 20480 B
    __shared__ int cnt[640];
    __shared__ int rs_[640];
    __shared__ int wsum[16];
    int k = blockIdx.x;
    int rbase = k * ECAP;
    int ne = min(gcur[k * GSTR], ECAP);
    for (int i = t; i < ne; i += 1024) eds[i] = coarse[rbase + i];
    if (t < 640) cnt[t] = 0;
    __syncthreads();
    int rr[MAXIT];
#pragma unroll
    for (int u = 0; u < MAXIT; ++u) {
        int i = t + u * 1024;
        rr[u] = 0;
        if (i < ne)
            rr[u] = atomicAdd(&cnt[eds[i].x >> 18], 1);   // returning: rank
    }
    __syncthreads();
    int wid = t >> 6, lane = t & 63;
    if (t < 640) {                    // waves 0..9 (640 = 10*64)
        int v = cnt[t];
        int incl = v;
#pragma unroll
        for (int o = 1; o < 64; o <<= 1) {
            int add = __shfl_up(incl, o, 64);
            if (lane >= o) incl += add;
        }
        rs_[t] = incl - v;
        if (lane == 63) wsum[wid] = incl;
    }
    __syncthreads();
    if (t < 64) {
        int vv = (lane < 10) ? wsum[lane] : 0;
        int inc2 = vv;
#pragma unroll
        for (int o = 1; o < 16; o <<= 1) {
            int add = __shfl_up(inc2, o, 64);
            if (lane >= o) inc2 += add;
        }
        if (lane < 10) wsum[lane] = inc2 - vv;
    }
    __syncthreads();
    if (t < 640) rs_[t] += wsum[wid];
    __syncthreads();
    int nodes0 = k * NPB;
    int nb = min(NPB, N_NODES - nodes0);
    if (t < nb)
        rowinfo[nodes0 + t] = (uint)(rbase + rs_[t]) | ((uint)cnt[t] << 22);
    // atomic-free inverse permutation: iperm[sorted_pos] = source index
#pragma unroll
    for (int u = 0; u < MAXIT; ++u) {
        int i = t + u * 1024;
        if (i < ne) {
            int dl = eds[i].x >> 18;
            iperm[rs_[dl] + rr[u]] = (unsigned short)i;
        }
    }
    __syncthreads();
    // coalesced write-back: consecutive threads -> consecutive coarse slots
    for (int j = t; j < ne; j += 1024) {
        int2 ev = eds[iperm[j]];
        coarse[rbase + j] = make_int2(ev.x & 0x3FFFF, ev.y);   // strip dl
    }
}

// SpMM over bf16 rows (128B/row). R16 form: 8 nodes per wave, one octet
// (8 lanes x uint4 = full row) per node. Per round: octet cooperatively
// loads 8 epair entries (64B coalesced), shfl-broadcasts src/val, issues
// 8 independent row gathers, then FMAs. No cross-lane reduce; wave
// stores 1KB contiguous (8 rows).
__global__ __launch_bounds__(256) void spmm_kernel(
        const uint* __restrict__ rowinfo, const int2* __restrict__ epair,
        const uint* __restrict__ xin, uint* __restrict__ xout) {
    int wave = (blockIdx.x * 256 + threadIdx.x) >> 6;
    int lane = threadIdx.x & 63;
    int g = lane >> 3;                // octet id = node slot 0..7
    int l = lane & 7;                 // uint4 slot within row
    int n = wave * 8 + g;
    bool live = n < N_NODES;
    uint ri = live ? rowinfo[n] : 0u;
    int s = (int)(ri & 0x3FFFFFu);
    int e = live ? s + (int)(ri >> 22) : s;   // empty/dead: e==s skips loop
    int gbase = g * 8;
    v2f a0 = {0.f, 0.f}, a1 = {0.f, 0.f}, a2 = {0.f, 0.f}, a3 = {0.f, 0.f};
    for (int jb = s; jb < e; jb += 8) {
        int jl = jb + l;
        // cooperative 64B epair fetch; tail clamps to e-1 (same line, w=0)
        int2 ev = epair[jl < e ? jl : (e - 1)];
        float vw = (jl < e) ? __int_as_float(ev.y) : 0.f;
        int sx = ev.x;
        int srcs[8];
        float ws[8];
#pragma unroll
        for (int u = 0; u < 8; ++u) {
            srcs[u] = __shfl(sx, gbase + u, 64);
            ws[u]   = __shfl(vw, gbase + u, 64);
        }
        uint4 r[8];
#pragma unroll
        for (int u = 0; u < 8; ++u)
            r[u] = ((const uint4*)(xin + (size_t)srcs[u] * 32))[l];
#pragma unroll
        for (int u = 0; u < 8; ++u) {
            a0 += ws[u] * unpack_bf16x2(r[u].x);
            a1 += ws[u] * unpack_bf16x2(r[u].y);
            a2 += ws[u] * unpack_bf16x2(r[u].z);
            a3 += ws[u] * unpack_bf16x2(r[u].w);
        }
    }
    if (live) {
        uint4 o;
        o.x = pack_bf16(a0.x, a0.y);
        o.y = pack_bf16(a1.x, a1.y);
        o.z = pack_bf16(a2.x, a2.y);
        o.w = pack_bf16(a3.x, a3.y);
        ((uint4*)(xout + (size_t)n * 32))[l] = o;   // wave: 8 rows = 1KB contig
    }
}

// Layer-3 restricted to batch rows: one wave per batch node (2*BATCH waves).
// x3[n] = sum val*x2[src]; add x0 (fp32) + x1 + x2 (bf16); store fp32 row.
__global__ __launch_bounds__(256) void batch_row_kernel(
        const int* __restrict__ users, const int* __restrict__ items,
        const float* __restrict__ emb_user, const float* __restrict__ emb_item,
        const uint* __restrict__ x1, const uint* __restrict__ x2,
        const uint* __restrict__ rowinfo, const int2* __restrict__ epair,
        float4* __restrict__ rows) {
    int w = (blockIdx.x * 256 + threadIdx.x) >> 6;   // 0..2*BATCH-1
    int lane = threadIdx.x & 63;
    int g = lane >> 4;
    int l = lane & 15;        // uint2 slot: dims 4l..4l+3
    bool isU = w < BATCH;
    int b = isU ? w : w - BATCH;
    int idx = isU ? users[b] : items[b];
    int n = isU ? idx : N_USERS + idx;
    uint ri = rowinfo[n];
    int s = (int)(ri & 0x3FFFFFu);
    int e = s + (int)(ri >> 22);
    v2f a0 = {0.f, 0.f}, a1 = {0.f, 0.f};
    for (int j0 = s + g; j0 < e; j0 += 16) {
        int2 ev[4];
        float vv[4];
        uint2 rr[4];
#pragma unroll
        for (int u = 0; u < 4; ++u) {
            int j = j0 + 4 * u;
            bool p = (u == 0) || (j < e);
            ev[u] = epair[p ? j : j0];
            vv[u] = p ? __int_as_float(ev[u].y) : 0.f;
        }
#pragma unroll
        for (int u = 0; u < 4; ++u)
            rr[u] = ((const uint2*)(x2 + (size_t)ev[u].x * 32))[l];
#pragma unroll
        for (int u = 0; u < 4; ++u) {
            a0 += vv[u] * unpack_bf16x2(rr[u].x);
            a1 += vv[u] * unpack_bf16x2(rr[u].y);
        }
    }
#pragma unroll
    for (int off = 16; off < 64; off <<= 1) {
        a0.x += __shfl_xor(a0.x, off, 64);
        a0.y += __shfl_xor(a0.y, off, 64);
        a1.x += __shfl_xor(a1.x, off, 64);
        a1.y += __shfl_xor(a1.y, off, 64);
    }
    if (g == 0) {
        const float* t0row = isU ? (emb_user + (size_t)idx * DIM)
                                 : (emb_item + (size_t)idx * DIM);
        float4 x0 = ((const float4*)t0row)[l];
        uint2 w1 = ((const uint2*)(x1 + (size_t)n * 32))[l];
        uint2 w2 = ((const uint2*)(x2 + (size_t)n * 32))[l];
        v2f b10 = unpack_bf16x2(w1.x), b11 = unpack_bf16x2(w1.y);
        v2f b20 = unpack_bf16x2(w2.x), b21 = unpack_bf16x2(w2.y);
        float4 r;
        r.x = x0.x + b10.x + b20.x + a0.x;
        r.y = x0.y + b10.y + b20.y + a0.y;
        r.z = x0.z + b11.x + b21.x + a1.x;
        r.w = x0.w + b11.y + b21.y + a1.y;
        rows[(size_t)w * 16 + l] = r;
    }
}

// gamma[b] = dot(rows[b], rows[BATCH+b]) / 16
__global__ __launch_bounds__(256) void dot_kernel(const float* __restrict__ rows,
                                                  float* __restrict__ out) {
    int t = blockIdx.x * 256 + threadIdx.x;
    int b = t >> 6;
    int lane = t & 63;
    float p = rows[(size_t)b * DIM + lane] * rows[(size_t)(BATCH + b) * DIM + lane];
#pragma unroll
    for (int o = 32; o > 0; o >>= 1) p += __shfl_down(p, o, 64);
    if (lane == 0) out[b] = p * (1.0f / 16.0f);
}

extern "C" void kernel_launch(void* const* d_in, const int* in_sizes, int n_in,
                              void* d_out, int out_size, void* d_ws, size_t ws_size,
                              hipStream_t stream) {
    const float* emb_user = (const float*)d_in[0];
    const float* emb_item = (const float*)d_in[1];
    const float* vals     = (const float*)d_in[2];
    const int*   src      = (const int*)d_in[3];
    const int*   dst      = (const int*)d_in[4];
    const int*   users    = (const int*)d_in[5];
    const int*   items    = (const int*)d_in[6];
    float* out = (float*)d_out;

    char* ws = (char*)d_ws;
    size_t off = 0;
    auto walloc = [&](size_t bytes) -> void* {
        void* p = ws + off;
        off += (bytes + 255) & ~(size_t)255;
        return p;
    };
    const size_t ROWB = (size_t)N_NODES * DIM * 2;                  // 19.2 MB
    uint* t0          = (uint*)walloc(ROWB);                        // bf16 x0
    uint* x1          = (uint*)walloc(ROWB);
    uint* x2          = (uint*)walloc(ROWB);
    int2* coarse      = (int2*)walloc((size_t)KB * ECAP * 8);       // 21.0 MB
    int*  gcur        = (int*) walloc((size_t)KB * GSTR * 4);       // padded
    uint* rowinfo     = (uint*)walloc((size_t)N_NODES * 4);
    float4* rows      = (float4*)walloc((size_t)2 * BATCH * DIM * 4); // 2 MB

    hipMemsetAsync(gcur, 0, (size_t)KB * GSTR * 4, stream);

    // Build: partition sort, then fine sort (+ co-resident bf16 conversion)
    part_kernel<<<CHUNKS, 1024, 0, stream>>>(src, dst, vals, gcur, coarse);
    p4f_fine<<<KB + CONVB, 1024, 0, stream>>>(
        coarse, gcur, rowinfo, emb_user, emb_item, (uint2*)t0);

    // Layers 1,2 full; layer 3 batch-only + dot
    const int SPMM_BLOCKS = (N_NODES / 8 * 64 + 255) / 256;
    spmm_kernel<<<SPMM_BLOCKS, 256, 0, stream>>>(rowinfo, coarse, t0, x1);
    spmm_kernel<<<SPMM_BLOCKS, 256, 0, stream>>>(rowinfo, coarse, x1, x2);
    batch_row_kernel<<<(2 * BATCH) / 4, 256, 0, stream>>>(
        users, items, emb_user, emb_item, x1, x2, rowinfo, coarse, rows);
    dot_kernel<<<(BATCH * 64) / 256, 256, 0, stream>>>((const float*)rows, out);
}

// Round 9
// 235.872 us; speedup vs baseline: 1.0309x; 1.0309x over previous
//
#include <hip/hip_runtime.h>

// LightGCN propagation: 3x SpMM over fixed COO graph + batched dot epilogue.
// R22: conv blocks reverted to part's grid (R21 moving them into p4f's
// grid co-resided them with the 1-block/CU sort and the 77MB stream
// contended with p4f's own global phases: +7us). KEPT: p4f single-
// atomic-pass (returning hist rank -> atomic-free iperm, R21(1)).
// NEW: dot fused into batch_row -- one wave per (user,item) pair,
// half-wave per node (2 edge-groups x 16 lanes), cross-half shfl_xor(32)
// + in-wave dot, writes gamma directly. Removes dot dispatch + 4MB rows
// round-trip.
// R20: part CHUNKS=512 (2 blocks/CU), p4f coalesced write-back via LDS
// inverse permutation. R18: part = LDS counting sort, coalesced run
// write-out, padded gcur. spmm (R16): 8 nodes/wave octets, cooperative
// 64B epair fetch, 8-deep row-gather MLP; at the ~3.5TB/s random-128B-
// gather fabric ceiling (FETCH = 8 XCD x ~81% table, compulsory).
// Layer 3 batch-only (R10). bf16 rows (R5).

#define N_USERS 50000
#define N_ITEMS 100000
#define N_NODES 150000
#define N_EDGES 2400000
#define DIM 64
#define BATCH 4096

#define CHUNKS 512
#define CHUNK_EDGES 4688   // 512*4688 = 2400256 >= N_EDGES (tail guarded)
#define PPT 5              // ceil(4688/1024) edges per thread per pass
#define KB 256             // super-buckets
#define NPB 586            // nodes per bucket; 256*586 = 150016 >= N_NODES
#define ECAP 10240         // bucket capacity: mean 9375, sigma 97 -> +8.9 sigma
#define MAXIT 10           // ECAP/1024 strided iterations in p4f
#define GSTR 16            // gcur stride: 1 counter per 64B line
#define CONVB 2344         // ceil(2400000 float4 / 1024)

typedef unsigned int uint;
typedef float v2f __attribute__((ext_vector_type(2)));

__device__ __forceinline__ uint pack_bf16(float a, float b) {
    uint ua = __float_as_uint(a), ub = __float_as_uint(b);
    ua = (ua + 0x7FFFu + ((ua >> 16) & 1u)) >> 16;   // RTNE
    ub = (ub + 0x7FFFu + ((ub >> 16) & 1u)) >> 16;
    return ua | (ub << 16);
}

__device__ __forceinline__ v2f unpack_bf16x2(uint w) {
    v2f r;
    r.x = __uint_as_float(w << 16);
    r.y = __uint_as_float(w & 0xFFFF0000u);
    return r;
}

// PART: blocks [0,CHUNKS): LDS counting sort of the chunk's edges by
// super-bucket, then coalesced segment write-out into reserved fat runs.
// 2 blocks/CU. Blocks [CHUNKS,..): fp32 -> bf16 concat t0 (run after the
// sort blocks drain -- non-interfering, R21 lesson).
__global__ __launch_bounds__(1024) void part_kernel(
        const int* __restrict__ src, const int* __restrict__ dstA,
        const float* __restrict__ vals, int* __restrict__ gcur,
        int2* __restrict__ coarse,
        const float* __restrict__ emb_user, const float* __restrict__ emb_item,
        uint2* __restrict__ t0) {
    int t = threadIdx.x;
    if (blockIdx.x >= CHUNKS) {
        int i = (blockIdx.x - CHUNKS) * 1024 + t;  // float4 index, 2.4M total
        if (i < N_NODES * DIM / 4) {
            const int userN4 = N_USERS * DIM / 4; // 800000
            float4 v;
            if (i < userN4) v = ((const float4*)emb_user)[i];
            else            v = ((const float4*)emb_item)[i - userN4];
            t0[i] = make_uint2(pack_bf16(v.x, v.y), pack_bf16(v.z, v.w));
        }
        return;
    }
    __shared__ int2 stage[CHUNK_EDGES];              // 37504 B sorted payload
    __shared__ unsigned char stage_b[CHUNK_EDGES];   // 4688 B bucket ids
    __shared__ int h[KB];
    __shared__ int hoff[KB];
    __shared__ int delta[KB];
    __shared__ int wsum4[4];
    int c = blockIdx.x;
    if (t < KB) h[t] = 0;
    __syncthreads();
    int base = c * CHUNK_EDGES;
    int ecnt = min(CHUNK_EDGES, N_EDGES - base);     // tail chunk short
    int d_c[PPT];
    int r_c[PPT];
#pragma unroll
    for (int u = 0; u < PPT; ++u) {
        int i = t + u * 1024;
        d_c[u] = 0;
        r_c[u] = 0;
        if (i < ecnt) {
            int d = dstA[base + i];
            d_c[u] = d;
            // returning atomic: rank within (chunk,bucket); independent ->
            // pipelined across the unrolled iterations.
            r_c[u] = atomicAdd(&h[(int)((unsigned)d / NPB)], 1);
        }
    }
    __syncthreads();
    int lane = t & 63, wid = t >> 6;
    if (t < KB) {                     // 4-wave scan of 256 bucket counts
        int v = h[t];
        int incl = v;
#pragma unroll
        for (int o = 1; o < 64; o <<= 1) {
            int add = __shfl_up(incl, o, 64);
            if (lane >= o) incl += add;
        }
        hoff[t] = incl - v;
        if (lane == 63) wsum4[wid] = incl;
    }
    __syncthreads();
    if (t < 64) {
        int vv = (lane < 4) ? wsum4[lane] : 0;
        int inc2 = vv;
#pragma unroll
        for (int o = 1; o < 4; o <<= 1) {
            int add = __shfl_up(inc2, o, 64);
            if (lane >= o) inc2 += add;
        }
        if (lane < 4) wsum4[lane] = inc2 - vv;
    }
    __syncthreads();
    if (t < KB) {
        int off = hoff[t] + wsum4[t >> 6];           // chunk-local bucket start
        hoff[t] = off;
        int cb = atomicAdd(&gcur[t * GSTR], h[t]);   // reserve fat run (padded)
        delta[t] = t * ECAP + cb - off;              // sorted-pos -> coarse idx
    }
    __syncthreads();
    // pass 1.5: stage edges into sorted LDS slots
#pragma unroll
    for (int u = 0; u < PPT; ++u) {
        int i = t + u * 1024;
        if (i < ecnt) {
            int e = base + i;
            int d = d_c[u];
            int b = (int)((unsigned)d / NPB);
            int dl = d - b * NPB;
            int pos = hoff[b] + r_c[u];
            stage[pos] = make_int2(src[e] | (dl << 18), __float_as_int(vals[e]));
            stage_b[pos] = (unsigned char)b;
        }
    }
    __syncthreads();
    // pass 2: coalesced write-out (consecutive j -> consecutive coarse idx
    // within each per-bucket run of ~18 edges)
#pragma unroll
    for (int u = 0; u < PPT; ++u) {
        int j = t + u * 1024;
        if (j < ecnt) {
            int b = stage_b[j];
            int idx = j + delta[b];
            if (idx < (b + 1) * ECAP)                // overflow guard
                coarse[idx] = stage[j];
        }
    }
}

// P4F: per-super-bucket fine sort IN PLACE -- edges -> LDS, RETURNING-
// atomic hist (rank in regs), wave-shuffle scan, rowinfo emit,
// atomic-free inverse permutation, coalesced write-back.
__global__ __launch_bounds__(1024) void p4f_fine(int2* __restrict__ coarse,
                                                 const int* __restrict__ gcur,
                                                 uint* __restrict__ rowinfo) {
    __shared__ int2 eds[ECAP];              // 81920 B
    __shared__ unsigned short iperm[ECAP];  // 20480 B
    __shared__ int cnt[640];
    __shared__ int rs_[640];
    __shared__ int wsum[16];
    int k = blockIdx.x, t = threadIdx.x;
    int rbase = k * ECAP;
    int ne = min(gcur[k * GSTR], ECAP);
    for (int i = t; i < ne; i += 1024) eds[i] = coarse[rbase + i];
    if (t < 640) cnt[t] = 0;
    __syncthreads();
    int rr[MAXIT];
#pragma unroll
    for (int u = 0; u < MAXIT; ++u) {
        int i = t + u * 1024;
        rr[u] = 0;
        if (i < ne)
            rr[u] = atomicAdd(&cnt[eds[i].x >> 18], 1);   // returning: rank
    }
    __syncthreads();
    int wid = t >> 6, lane = t & 63;
    if (t < 640) {                    // waves 0..9 (640 = 10*64)
        int v = cnt[t];
        int incl = v;
#pragma unroll
        for (int o = 1; o < 64; o <<= 1) {
            int add = __shfl_up(incl, o, 64);
            if (lane >= o) incl += add;
        }
        rs_[t] = incl - v;
        if (lane == 63) wsum[wid] = incl;
    }
    __syncthreads();
    if (t < 64) {
        int vv = (lane < 10) ? wsum[lane] : 0;
        int inc2 = vv;
#pragma unroll
        for (int o = 1; o < 16; o <<= 1) {
            int add = __shfl_up(inc2, o, 64);
            if (lane >= o) inc2 += add;
        }
        if (lane < 10) wsum[lane] = inc2 - vv;
    }
    __syncthreads();
    if (t < 640) rs_[t] += wsum[wid];
    __syncthreads();
    int nodes0 = k * NPB;
    int nb = min(NPB, N_NODES - nodes0);
    if (t < nb)
        rowinfo[nodes0 + t] = (uint)(rbase + rs_[t]) | ((uint)cnt[t] << 22);
    // atomic-free inverse permutation: iperm[sorted_pos] = source index
#pragma unroll
    for (int u = 0; u < MAXIT; ++u) {
        int i = t + u * 1024;
        if (i < ne) {
            int dl = eds[i].x >> 18;
            iperm[rs_[dl] + rr[u]] = (unsigned short)i;
        }
    }
    __syncthreads();
    // coalesced write-back: consecutive threads -> consecutive coarse slots
    for (int j = t; j < ne; j += 1024) {
        int2 ev = eds[iperm[j]];
        coarse[rbase + j] = make_int2(ev.x & 0x3FFFF, ev.y);   // strip dl
    }
}

// SpMM over bf16 rows (128B/row). R16 form: 8 nodes per wave, one octet
// (8 lanes x uint4 = full row) per node. Per round: octet cooperatively
// loads 8 epair entries (64B coalesced), shfl-broadcasts src/val, issues
// 8 independent row gathers, then FMAs. No cross-lane reduce; wave
// stores 1KB contiguous (8 rows).
__global__ __launch_bounds__(256) void spmm_kernel(
        const uint* __restrict__ rowinfo, const int2* __restrict__ epair,
        const uint* __restrict__ xin, uint* __restrict__ xout) {
    int wave = (blockIdx.x * 256 + threadIdx.x) >> 6;
    int lane = threadIdx.x & 63;
    int g = lane >> 3;                // octet id = node slot 0..7
    int l = lane & 7;                 // uint4 slot within row
    int n = wave * 8 + g;
    bool live = n < N_NODES;
    uint ri = live ? rowinfo[n] : 0u;
    int s = (int)(ri & 0x3FFFFFu);
    int e = live ? s + (int)(ri >> 22) : s;   // empty/dead: e==s skips loop
    int gbase = g * 8;
    v2f a0 = {0.f, 0.f}, a1 = {0.f, 0.f}, a2 = {0.f, 0.f}, a3 = {0.f, 0.f};
    for (int jb = s; jb < e; jb += 8) {
        int jl = jb + l;
        // cooperative 64B epair fetch; tail clamps to e-1 (same line, w=0)
        int2 ev = epair[jl < e ? jl : (e - 1)];
        float vw = (jl < e) ? __int_as_float(ev.y) : 0.f;
        int sx = ev.x;
        int srcs[8];
        float ws[8];
#pragma unroll
        for (int u = 0; u < 8; ++u) {
            srcs[u] = __shfl(sx, gbase + u, 64);
            ws[u]   = __shfl(vw, gbase + u, 64);
        }
        uint4 r[8];
#pragma unroll
        for (int u = 0; u < 8; ++u)
            r[u] = ((const uint4*)(xin + (size_t)srcs[u] * 32))[l];
#pragma unroll
        for (int u = 0; u < 8; ++u) {
            a0 += ws[u] * unpack_bf16x2(r[u].x);
            a1 += ws[u] * unpack_bf16x2(r[u].y);
            a2 += ws[u] * unpack_bf16x2(r[u].z);
            a3 += ws[u] * unpack_bf16x2(r[u].w);
        }
    }
    if (live) {
        uint4 o;
        o.x = pack_bf16(a0.x, a0.y);
        o.y = pack_bf16(a1.x, a1.y);
        o.z = pack_bf16(a2.x, a2.y);
        o.w = pack_bf16(a3.x, a3.y);
        ((uint4*)(xout + (size_t)n * 32))[l] = o;   // wave: 8 rows = 1KB contig
    }
}

// Layer 3 + dot, fused: one wave per (user,item) pair. Half-wave per
// node (lanes 0-31 user, 32-63 item); within a half, 2 edge-groups x 16
// lanes; each lane owns dims 4l..4l+3 (uint2 slot l). After the x3
// gather: reduce across edge-groups (xor 16), add x0+x1+x2, cross-half
// shfl_xor(32) brings the partner row, in-wave dot, lane 0 writes gamma.
__global__ __launch_bounds__(256) void batch_dot_kernel(
        const int* __restrict__ users, const int* __restrict__ items,
        const float* __restrict__ emb_user, const float* __restrict__ emb_item,
        const uint* __restrict__ x1, const uint* __restrict__ x2,
        const uint* __restrict__ rowinfo, const int2* __restrict__ epair,
        float* __restrict__ out) {
    int b = (blockIdx.x * 256 + threadIdx.x) >> 6;   // 0..BATCH-1
    int lane = threadIdx.x & 63;
    int hg = (lane >> 4) & 1;  // edge-group within half
    int l = lane & 15;         // uint2 slot: dims 4l..4l+3
    bool isU = lane < 32;
    int idx = isU ? users[b] : items[b];
    int n = isU ? idx : N_USERS + idx;
    uint ri = rowinfo[n];
    int s = (int)(ri & 0x3FFFFFu);
    int e = s + (int)(ri >> 22);
    v2f a0 = {0.f, 0.f}, a1 = {0.f, 0.f};
    for (int j0 = s + hg; j0 < e; j0 += 8) {
        int2 ev[4];
        float vv[4];
        uint2 rr[4];
#pragma unroll
        for (int u = 0; u < 4; ++u) {
            int j = j0 + 2 * u;
            bool p = (u == 0) || (j < e);
            ev[u] = epair[p ? j : j0];
            vv[u] = p ? __int_as_float(ev[u].y) : 0.f;
        }
#pragma unroll
        for (int u = 0; u < 4; ++u)
            rr[u] = ((const uint2*)(x2 + (size_t)ev[u].x * 32))[l];
#pragma unroll
        for (int u = 0; u < 4; ++u) {
            a0 += vv[u] * unpack_bf16x2(rr[u].x);
            a1 += vv[u] * unpack_bf16x2(rr[u].y);
        }
    }
    // reduce across the 2 edge-groups (stays within each half)
    a0.x += __shfl_xor(a0.x, 16, 64);
    a0.y += __shfl_xor(a0.y, 16, 64);
    a1.x += __shfl_xor(a1.x, 16, 64);
    a1.y += __shfl_xor(a1.y, 16, 64);
    // epilogue: r = x0 + x1 + x2 + x3 for this node's dims 4l..4l+3
    const float* t0row = isU ? (emb_user + (size_t)idx * DIM)
                             : (emb_item + (size_t)idx * DIM);
    float4 x0 = ((const float4*)t0row)[l];
    uint2 w1 = ((const uint2*)(x1 + (size_t)n * 32))[l];
    uint2 w2 = ((const uint2*)(x2 + (size_t)n * 32))[l];
    v2f b10 = unpack_bf16x2(w1.x), b11 = unpack_bf16x2(w1.y);
    v2f b20 = unpack_bf16x2(w2.x), b21 = unpack_bf16x2(w2.y);
    float rx = x0.x + b10.x + b20.x + a0.x;
    float ry = x0.y + b10.y + b20.y + a0.y;
    float rz = x0.z + b11.x + b21.x + a1.x;
    float rw = x0.w + b11.y + b21.y + a1.y;
    // cross-half: partner row's same dims
    float ox = __shfl_xor(rx, 32, 64);
    float oy = __shfl_xor(ry, 32, 64);
    float oz = __shfl_xor(rz, 32, 64);
    float ow = __shfl_xor(rw, 32, 64);
    float p = rx * ox + ry * oy + rz * oz + rw * ow;
#pragma unroll
    for (int o = 1; o < 16; o <<= 1) p += __shfl_xor(p, o, 64);
    if (lane == 0) out[b] = p * (1.0f / 16.0f);
}

extern "C" void kernel_launch(void* const* d_in, const int* in_sizes, int n_in,
                              void* d_out, int out_size, void* d_ws, size_t ws_size,
                              hipStream_t stream) {
    const float* emb_user = (const float*)d_in[0];
    const float* emb_item = (const float*)d_in[1];
    const float* vals     = (const float*)d_in[2];
    const int*   src      = (const int*)d_in[3];
    const int*   dst      = (const int*)d_in[4];
    const int*   users    = (const int*)d_in[5];
    const int*   items    = (const int*)d_in[6];
    float* out = (float*)d_out;

    char* ws = (char*)d_ws;
    size_t off = 0;
    auto walloc = [&](size_t bytes) -> void* {
        void* p = ws + off;
        off += (bytes + 255) & ~(size_t)255;
        return p;
    };
    const size_t ROWB = (size_t)N_NODES * DIM * 2;                  // 19.2 MB
    uint* t0          = (uint*)walloc(ROWB);                        // bf16 x0
    uint* x1          = (uint*)walloc(ROWB);
    uint* x2          = (uint*)walloc(ROWB);
    int2* coarse      = (int2*)walloc((size_t)KB * ECAP * 8);       // 21.0 MB
    int*  gcur        = (int*) walloc((size_t)KB * GSTR * 4);       // padded
    uint* rowinfo     = (uint*)walloc((size_t)N_NODES * 4);

    hipMemsetAsync(gcur, 0, (size_t)KB * GSTR * 4, stream);

    // Build: partition sort (+ trailing bf16 conversion), then fine sort
    part_kernel<<<CHUNKS + CONVB, 1024, 0, stream>>>(
        src, dst, vals, gcur, coarse, emb_user, emb_item, (uint2*)t0);
    p4f_fine<<<KB, 1024, 0, stream>>>(coarse, gcur, rowinfo);

    // Layers 1,2 full; layer 3 + dot fused, batch-only
    const int SPMM_BLOCKS = (N_NODES / 8 * 64 + 255) / 256;
    spmm_kernel<<<SPMM_BLOCKS, 256, 0, stream>>>(rowinfo, coarse, t0, x1);
    spmm_kernel<<<SPMM_BLOCKS, 256, 0, stream>>>(rowinfo, coarse, x1, x2);
    batch_dot_kernel<<<(BATCH * 64) / 256, 256, 0, stream>>>(
        users, items, emb_user, emb_item, x1, x2, rowinfo, coarse, out);
}